// Round 9
// baseline (223.117 us; speedup 1.0000x reference)
//
#include <hip/hip_runtime.h>
#include <hip/hip_bf16.h>

// B=1, S=8, N=512, DV=256, DM=64, INNER=256, H=8, WS=3, DH=32
#define S_ 8
#define N_ 512
#define DV_ 256
#define DM_ 64
#define INNER_ 256
#define H_ 8
#define WS_ 3
#define DH_ 32

typedef __attribute__((ext_vector_type(8))) __bf16 bf16x8;
typedef __attribute__((ext_vector_type(4))) float f32x4;

__device__ __forceinline__ float clip5(float x) {
    return fminf(5.0f, fmaxf(-5.0f, x));
}
__device__ __forceinline__ unsigned short f2bf(float x) {
    __hip_bfloat16 h = __float2bfloat16(x);
    return *reinterpret_cast<unsigned short*>(&h);
}

// ---------------------------------------------------------------------------
// Kernel 0: prep — weight transposes (f32 -> bf16 W^T[n][k]) + meta_mean parts
// blocks 0..47:  w_qkv [256][768] -> WqkvT [768][256]
// blocks 48..55: w_meta_inner [64][512] -> WmetaT [512][64]
// blocks 56..119: meta partial sums: block 56+s*8+g sums tokens [g*64,(g+1)*64)
// ---------------------------------------------------------------------------
__global__ __launch_bounds__(256) void prep(
    const float* __restrict__ w_qkv, const float* __restrict__ w_meta_inner,
    const float* __restrict__ metadata,
    unsigned short* __restrict__ WqkvT, unsigned short* __restrict__ WmetaT,
    float* __restrict__ mm_part)
{
    __shared__ float Tf[64][65];
    int b = blockIdx.x, tid = threadIdx.x;
    if (b < 56) {
        const float* src; unsigned short* dst; int Nsrc, Ktot, k0, n0;
        if (b < 48) { src = w_qkv;        dst = WqkvT;  Nsrc = 768; Ktot = 256; k0 = (b & 3) * 64; n0 = (b >> 2) * 64; }
        else        { src = w_meta_inner; dst = WmetaT; Nsrc = 512; Ktot = 64;  k0 = 0;            n0 = (b - 48) * 64; }
#pragma unroll
        for (int p = 0; p < 16; p++) {
            int i = p * 256 + tid; int r = i >> 6, cc = i & 63;
            Tf[r][cc] = src[(size_t)(k0 + r) * Nsrc + n0 + cc];
        }
        __syncthreads();
#pragma unroll
        for (int p = 0; p < 16; p++) {
            int i = p * 256 + tid; int r = i >> 6, cc = i & 63;
            dst[(size_t)(n0 + r) * Ktot + k0 + cc] = f2bf(Tf[cc][r]);
        }
    } else {
        int bb = b - 56;          // 0..63
        int s = bb >> 3, g = bb & 7;
        int d = tid & 63, t4 = tid >> 6;
        const float* base = metadata + ((size_t)(s * N_) + g * 64 + t4 * 16) * DM_ + d;
        float acc = 0.f;
#pragma unroll
        for (int i = 0; i < 16; i++) acc += base[(size_t)i * DM_];
        float* red = &Tf[0][0];
        red[tid] = acc;
        __syncthreads();
        if (tid < 64)
            mm_part[(size_t)bb * 64 + tid] =
                red[tid] + red[tid + 64] + red[tid + 128] + red[tid + 192];
    }
}

// ---------------------------------------------------------------------------
// GEMM body (64x64 tile, 4 waves of 32x32), A f32 -> bf16 staged, Bt pre-bf16.
// ROLE 0: values @ WqkvT -> Qc/Kc (clip, qp|kp halves) + Vt
// ROLE 1: metadata @ WmetaT -> Qc/Kc (clip, qm|km halves)
// ---------------------------------------------------------------------------
template<int ROLE>
__device__ __forceinline__ void gemm_body(
    unsigned short* smem,
    const float* __restrict__ A, const unsigned short* __restrict__ Bt,
    unsigned short* __restrict__ Qc, unsigned short* __restrict__ Kc,
    unsigned short* __restrict__ Vt,
    int m0, int n0g, int tid)
{
    constexpr int K = (ROLE == 1) ? 64 : 256;
    constexpr int KP = K + 8;
    unsigned short* As = smem;
    unsigned short* Bs = smem + 64 * KP;

    for (int i = tid; i < 64 * (K / 4); i += 256) {
        int r = i / (K / 4), g = i % (K / 4);
        float4 x = *(const float4*)(A + (size_t)(m0 + r) * K + 4 * g);
        *(ushort4*)&As[r * KP + 4 * g] =
            make_ushort4(f2bf(x.x), f2bf(x.y), f2bf(x.z), f2bf(x.w));
    }
    for (int i = tid; i < 64 * (K / 8); i += 256) {
        int r = i / (K / 8), g = i % (K / 8);
        *(bf16x8*)&Bs[r * KP + 8 * g] =
            *(const bf16x8*)(Bt + (size_t)(n0g + r) * K + 8 * g);
    }
    __syncthreads();

    const int w = tid >> 6, lane = tid & 63, c = lane & 15, qd = lane >> 4;
    const int mb = (w >> 1) * 32, nb = (w & 1) * 32;
    f32x4 acc[2][2];
    const f32x4 z = {0.f, 0.f, 0.f, 0.f};
#pragma unroll
    for (int mt = 0; mt < 2; mt++)
#pragma unroll
        for (int nt = 0; nt < 2; nt++) acc[mt][nt] = z;

#pragma unroll
    for (int kk = 0; kk < K / 32; kk++) {
        bf16x8 a[2], bb[2];
#pragma unroll
        for (int mt = 0; mt < 2; mt++)
            a[mt] = *(const bf16x8*)&As[(mb + mt * 16 + c) * KP + kk * 32 + qd * 8];
#pragma unroll
        for (int nt = 0; nt < 2; nt++)
            bb[nt] = *(const bf16x8*)&Bs[(nb + nt * 16 + c) * KP + kk * 32 + qd * 8];
#pragma unroll
        for (int mt = 0; mt < 2; mt++)
#pragma unroll
            for (int nt = 0; nt < 2; nt++)
                acc[mt][nt] = __builtin_amdgcn_mfma_f32_16x16x32_bf16(
                    a[mt], bb[nt], acc[mt][nt], 0, 0, 0);
    }

#pragma unroll
    for (int mt = 0; mt < 2; mt++)
#pragma unroll
        for (int nt = 0; nt < 2; nt++)
#pragma unroll
            for (int r = 0; r < 4; r++) {
                int tok = m0 + mb + mt * 16 + qd * 4 + r;
                int n = n0g + nb + nt * 16 + c;
                float v = acc[mt][nt][r];
                if (ROLE == 0) {
                    if (n < 512) {
                        unsigned short* dst = (n < 256) ? Qc : Kc;
                        int p = n & 255;
                        dst[(size_t)tok * 512 + (p >> 5) * 64 + (p & 31)] = f2bf(clip5(v));
                    } else {
                        int vc = n - 512, h = vc >> 5, dh = vc & 31;
                        int s = tok >> 9, ntok = tok & 511;
                        Vt[(size_t)((s * 8 + h) * 32 + dh) * 512 + ntok] = f2bf(v);
                    }
                } else {
                    unsigned short* dst = (n < 256) ? Qc : Kc;
                    int p = n & 255;
                    dst[(size_t)tok * 512 + (p >> 5) * 64 + 32 + (p & 31)] = f2bf(clip5(v));
                }
            }
}

// ---------------------------------------------------------------------------
// Kernel 1: fused — block 0: cnt zero + mm reduce + outer topk;
// blocks 1..768: values GEMM; blocks 769..1280: metadata GEMM.
// ---------------------------------------------------------------------------
__global__ __launch_bounds__(256) void fused1(
    const float* __restrict__ values, const float* __restrict__ metadata,
    const unsigned short* __restrict__ WqkvT,
    const unsigned short* __restrict__ WmetaT,
    const float* __restrict__ mm_part, const float* __restrict__ w_meta_outer,
    unsigned short* __restrict__ Qc, unsigned short* __restrict__ Kc,
    unsigned short* __restrict__ Vt, int* __restrict__ topidx,
    unsigned int* __restrict__ cnt)
{
    __shared__ __align__(16) unsigned short smem[2 * 64 * 264];  // 66 KB
    const int b = blockIdx.x, tid = threadIdx.x;

    if (b == 0) {
        if (tid < 64) cnt[tid] = 0u;  // completion counters for attn epilogue
        float* mml  = (float*)smem;            // [8][64]
        float* qmS  = mml + 512;               // [8][256]
        float* kmS  = qmS + 2048;              // [8][256]
        float* dots = kmS + 2048;              // [8][8]
        for (int i = tid; i < 512; i += 256) {
            int s = i >> 6, d = i & 63;
            float acc = 0.f;
#pragma unroll
            for (int g = 0; g < 8; g++) acc += mm_part[(size_t)(s * 8 + g) * 64 + d];
            mml[i] = acc * (1.0f / (float)N_);
        }
        __syncthreads();
        for (int i = tid; i < S_ * 512; i += 256) {
            int s = i >> 9, c = i & 511;
            float acc = 0.0f;
            for (int k = 0; k < DM_; k++) acc += mml[s * 64 + k] * w_meta_outer[k * 512 + c];
            acc = clip5(acc);
            if (c < 256) qmS[s * 256 + c] = acc; else kmS[s * 256 + c - 256] = acc;
        }
        __syncthreads();
        if (tid < 64) {
            int qi = tid >> 3, ki = tid & 7;
            float acc = 0.0f;
            for (int j = 0; j < INNER_; j++) acc += qmS[qi * 256 + j] * kmS[ki * 256 + j];
            dots[qi * 8 + ki] = acc * 0.0625f;  // 1/sqrt(256)
        }
        __syncthreads();
        if (tid < S_) {
            int r = tid;
            float mx = -1e30f;
            for (int k = 0; k < S_; k++) mx = fmaxf(mx, dots[r * 8 + k]);
            float e[S_], sum = 0.0f;
            for (int k = 0; k < S_; k++) { e[k] = __expf(dots[r * 8 + k] - mx); sum += e[k]; }
            float vals[S_];
            for (int k = 0; k < S_; k++) vals[k] = e[k] / sum + (k == r ? 2.0f : 0.0f);
            bool used[S_];
            for (int k = 0; k < S_; k++) used[k] = false;
            for (int w = 0; w < WS_; w++) {
                float best = -1e30f; int bi = 0;
                for (int k = 0; k < S_; k++) {
                    if (!used[k] && vals[k] > best) { best = vals[k]; bi = k; }
                }
                used[bi] = true;
                topidx[r * WS_ + w] = bi;
            }
        }
    } else if (b <= 768) {
        int g = b - 1;
        gemm_body<0>(smem, values, WqkvT, Qc, Kc, Vt, (g & 63) * 64, (g >> 6) * 64, tid);
    } else {
        int g = b - 769;
        gemm_body<1>(smem, metadata, WmetaT, Qc, Kc, Vt, (g & 63) * 64, (g >> 6) * 64, tid);
    }
}

// ---------------------------------------------------------------------------
// Kernel 2: MFMA flash attention + fused last-arriver output projection.
// Block (s,h,qt) computes AO chunk [64 tok][head h 32 ch]; the 8th finisher
// per (s,qt) also computes out[64,256] = AO[64,256] @ w_out + b_out.
// ---------------------------------------------------------------------------
__global__ __launch_bounds__(256) void attn_mfma(
    const int* __restrict__ topidx,
    const unsigned short* __restrict__ Qc,   // [4096][8][64] bf16
    const unsigned short* __restrict__ Kc,   // [4096][8][64] bf16
    const unsigned short* __restrict__ Vt,   // [8][8][32][512] bf16
    unsigned short* __restrict__ AO,         // [4096][256] bf16
    const float* __restrict__ w_out,         // [256][256] f32
    const float* __restrict__ b_out,         // [256] f32
    float* __restrict__ outp,                // [4096][256] f32
    unsigned int* __restrict__ cnt)          // [64] completion counters
{
    const int s   = blockIdx.x;
    const int h   = blockIdx.y;
    const int qt  = blockIdx.z;
    const int tid = threadIdx.x;
    const int w    = tid >> 6;
    const int lane = tid & 63;
    const int c    = lane & 15;
    const int qd   = lane >> 4;
    const float scale = 0.17677669529663687f;  // 1/sqrt(32)

    __shared__ __align__(16) unsigned char smemraw[67584];
    unsigned short (*Pq)[64][40] = (unsigned short(*)[64][40])smemraw;   // 20480 B
    float (*Of)[32][66] = (float(*)[32][66])(smemraw + 20480);           // 33792 B
    float (*Ml)[2][64]  = (float(*)[2][64])(smemraw + 54272);            // 2048 B
    __shared__ int lastflag;

    const int src0 = topidx[s * WS_ + 0];
    const int srcs[3] = { topidx[s * WS_ + 0], topidx[s * WS_ + 1], topidx[s * WS_ + 2] };

    bf16x8 qf[4][2];
    {
        const unsigned short* qbase =
            Qc + (size_t)(src0 * N_ + qt * 64) * 512 + h * 64 + qd * 8;
#pragma unroll
        for (int qg = 0; qg < 4; qg++)
#pragma unroll
            for (int kc = 0; kc < 2; kc++)
                qf[qg][kc] = *reinterpret_cast<const bf16x8*>(
                    qbase + (size_t)(qg * 16 + c) * 512 + kc * 32);
    }

    f32x4 oacc[2][4];
    const f32x4 zero4 = {0.f, 0.f, 0.f, 0.f};
#pragma unroll
    for (int mg = 0; mg < 2; mg++)
#pragma unroll
        for (int qg = 0; qg < 4; qg++) oacc[mg][qg] = zero4;
    float mrun[4], lrun[4];
#pragma unroll
    for (int qg = 0; qg < 4; qg++) { mrun[qg] = -3.0e38f; lrun[qg] = 0.f; }

    for (int step = 0; step < 12; step++) {
        const int chunk = step * 4 + w;
        const int src = srcs[chunk >> 4];
        const int klocal = (chunk & 15) * 32;

        bf16x8 kf[2][2];
        const unsigned short* kbase =
            Kc + (size_t)(src * N_ + klocal) * 512 + h * 64 + qd * 8;
#pragma unroll
        for (int mg = 0; mg < 2; mg++)
#pragma unroll
            for (int kc = 0; kc < 2; kc++)
                kf[mg][kc] = *reinterpret_cast<const bf16x8*>(
                    kbase + (size_t)(mg * 16 + c) * 512 + kc * 32);

        bf16x8 vf[2];
        const unsigned short* vbase =
            Vt + (size_t)((src * H_ + h) * DH_) * N_ + klocal + qd * 8;
#pragma unroll
        for (int mg = 0; mg < 2; mg++)
            vf[mg] = *reinterpret_cast<const bf16x8*>(vbase + (size_t)(mg * 16 + c) * N_);

        f32x4 sacc[2][4];
#pragma unroll
        for (int mg = 0; mg < 2; mg++)
#pragma unroll
            for (int qg = 0; qg < 4; qg++) sacc[mg][qg] = zero4;
#pragma unroll
        for (int kc = 0; kc < 2; kc++)
#pragma unroll
            for (int mg = 0; mg < 2; mg++)
#pragma unroll
                for (int qg = 0; qg < 4; qg++)
                    sacc[mg][qg] = __builtin_amdgcn_mfma_f32_16x16x32_bf16(
                        kf[mg][kc], qf[qg][kc], sacc[mg][qg], 0, 0, 0);

#pragma unroll
        for (int qg = 0; qg < 4; qg++) {
            float mx = sacc[0][qg][0];
#pragma unroll
            for (int r = 1; r < 4; r++) mx = fmaxf(mx, sacc[0][qg][r]);
#pragma unroll
            for (int r = 0; r < 4; r++) mx = fmaxf(mx, sacc[1][qg][r]);
            mx = fmaxf(mx, __shfl_xor(mx, 16));
            mx = fmaxf(mx, __shfl_xor(mx, 32));
            float mnew = fmaxf(mrun[qg], mx);
            float alpha = __expf((mrun[qg] - mnew) * scale);
            float msc = mnew * scale;
            float ps = 0.f;
            unsigned short pb[2][4];
#pragma unroll
            for (int mg = 0; mg < 2; mg++)
#pragma unroll
                for (int r = 0; r < 4; r++) {
                    float p = __expf(__builtin_fmaf(sacc[mg][qg][r], scale, -msc));
                    ps += p;
                    pb[mg][r] = f2bf(p);
                }
            ps += __shfl_xor(ps, 16);
            ps += __shfl_xor(ps, 32);
            lrun[qg] = lrun[qg] * alpha + ps;
            mrun[qg] = mnew;
#pragma unroll
            for (int mg = 0; mg < 2; mg++)
#pragma unroll
                for (int r = 0; r < 4; r++) oacc[mg][qg][r] *= alpha;
#pragma unroll
            for (int mg = 0; mg < 2; mg++) {
                ushort4 u = make_ushort4(pb[mg][0], pb[mg][1], pb[mg][2], pb[mg][3]);
                *reinterpret_cast<ushort4*>(&Pq[w][qg * 16 + c][mg * 16 + qd * 4]) = u;
            }
        }

        bf16x8 pf[4];
#pragma unroll
        for (int qg = 0; qg < 4; qg++)
            pf[qg] = *reinterpret_cast<const bf16x8*>(&Pq[w][qg * 16 + c][qd * 8]);
#pragma unroll
        for (int mg = 0; mg < 2; mg++)
#pragma unroll
            for (int qg = 0; qg < 4; qg++)
                oacc[mg][qg] = __builtin_amdgcn_mfma_f32_16x16x32_bf16(
                    vf[mg], pf[qg], oacc[mg][qg], 0, 0, 0);
    }

    __syncthreads();
#pragma unroll
    for (int qg = 0; qg < 4; qg++) {
        if (qd == 0) {
            (*Ml)[0][0] = (*Ml)[0][0];  // no-op to keep type; real writes below
        }
    }
#pragma unroll
    for (int qg = 0; qg < 4; qg++) {
        if (qd == 0) {
            Ml[w][0][qg * 16 + c] = mrun[qg];
            Ml[w][1][qg * 16 + c] = lrun[qg];
        }
#pragma unroll
        for (int mg = 0; mg < 2; mg++)
#pragma unroll
            for (int r = 0; r < 4; r++)
                Of[w][mg * 16 + qd * 4 + r][qg * 16 + c] = oacc[mg][qg][r];
    }
    __syncthreads();

    {
        int q = tid & 63;
        int dh0 = (tid >> 6) * 8;
        float mw[4], cw[4];
#pragma unroll
        for (int v = 0; v < 4; v++) mw[v] = Ml[v][0][q];
        float M = fmaxf(fmaxf(mw[0], mw[1]), fmaxf(mw[2], mw[3]));
        float L = 0.f;
#pragma unroll
        for (int v = 0; v < 4; v++) {
            cw[v] = __expf((mw[v] - M) * scale);
            L += cw[v] * Ml[v][1][q];
        }
        float inv = 1.0f / L;
        unsigned short* aorow =
            AO + (size_t)(s * N_ + qt * 64 + q) * 256 + h * 32 + dh0;
        unsigned short ub[8];
#pragma unroll
        for (int j = 0; j < 8; j++) {
            int dh = dh0 + j;
            float o = cw[0] * Of[0][dh][q] + cw[1] * Of[1][dh][q]
                    + cw[2] * Of[2][dh][q] + cw[3] * Of[3][dh][q];
            ub[j] = f2bf(o * inv);
        }
        uint4 u;
        u.x = (unsigned)ub[0] | ((unsigned)ub[1] << 16);
        u.y = (unsigned)ub[2] | ((unsigned)ub[3] << 16);
        u.z = (unsigned)ub[4] | ((unsigned)ub[5] << 16);
        u.w = (unsigned)ub[6] | ((unsigned)ub[7] << 16);
        *reinterpret_cast<uint4*>(aorow) = u;
    }

    // ---- last-arriver ticket: 8th finisher of (s,qt) does the out-proj ----
    __threadfence();
    __syncthreads();
    if (tid == 0) {
        unsigned int old = __hip_atomic_fetch_add(&cnt[s * 8 + qt], 1u,
                                                  __ATOMIC_ACQ_REL,
                                                  __HIP_MEMORY_SCOPE_AGENT);
        lastflag = (old == 7u) ? 1 : 0;
    }
    __syncthreads();
    if (!lastflag) return;
    __threadfence();  // acquire: other blocks' AO writes

    {
        constexpr int K = 256, KP = 264;
        unsigned short* As = (unsigned short*)smemraw;        // 64*264*2 = 33792
        unsigned short* Bs = (unsigned short*)(smemraw + 33792);
        const int t0 = s * N_ + qt * 64;

        for (int i = tid; i < 64 * 32; i += 256) {
            int r = i >> 5, g = i & 31;
            *(bf16x8*)&As[r * KP + 8 * g] =
                *(const bf16x8*)(AO + (size_t)(t0 + r) * K + 8 * g);
        }
        for (int nchunk = 0; nchunk < 4; nchunk++) {
            __syncthreads();
            // stage w_out[k][nchunk*64 .. +64] f32 -> Bs[n][k] bf16 (rotated)
            for (int i = tid; i < K * 16; i += 256) {
                int k = i >> 4, a = i & 15, n4 = a * 4;
                float4 x = *(const float4*)(w_out + (size_t)k * 256 + nchunk * 64 + n4);
                float xs[4] = {x.x, x.y, x.z, x.w};
#pragma unroll
                for (int j = 0; j < 4; j++) {
                    int cs = (j + a) & 3;
                    Bs[(n4 + cs) * KP + k] = f2bf(xs[cs]);
                }
            }
            __syncthreads();

            const int mb = (w >> 1) * 32, nb = (w & 1) * 32;
            f32x4 acc[2][2];
#pragma unroll
            for (int mt = 0; mt < 2; mt++)
#pragma unroll
                for (int nt = 0; nt < 2; nt++) acc[mt][nt] = zero4;
#pragma unroll
            for (int kk = 0; kk < K / 32; kk++) {
                bf16x8 a[2], bb[2];
#pragma unroll
                for (int mt = 0; mt < 2; mt++)
                    a[mt] = *(const bf16x8*)&As[(mb + mt * 16 + c) * KP + kk * 32 + qd * 8];
#pragma unroll
                for (int nt = 0; nt < 2; nt++)
                    bb[nt] = *(const bf16x8*)&Bs[(nb + nt * 16 + c) * KP + kk * 32 + qd * 8];
#pragma unroll
                for (int mt = 0; mt < 2; mt++)
#pragma unroll
                    for (int nt = 0; nt < 2; nt++)
                        acc[mt][nt] = __builtin_amdgcn_mfma_f32_16x16x32_bf16(
                            a[mt], bb[nt], acc[mt][nt], 0, 0, 0);
            }
#pragma unroll
            for (int mt = 0; mt < 2; mt++)
#pragma unroll
                for (int nt = 0; nt < 2; nt++)
#pragma unroll
                    for (int r = 0; r < 4; r++) {
                        int tok = t0 + mb + mt * 16 + qd * 4 + r;
                        int n = nchunk * 64 + nb + nt * 16 + c;
                        outp[(size_t)tok * 256 + n] = acc[mt][nt][r] + b_out[n];
                    }
        }
    }
}

// ---------------------------------------------------------------------------
extern "C" void kernel_launch(void* const* d_in, const int* in_sizes, int n_in,
                              void* d_out, int out_size, void* d_ws, size_t ws_size,
                              hipStream_t stream) {
    const float* values       = (const float*)d_in[0];  // [1,8,512,256]
    const float* metadata     = (const float*)d_in[1];  // [1,8,512,64]
    const float* w_meta_outer = (const float*)d_in[2];  // [64,512]
    const float* w_qkv        = (const float*)d_in[3];  // [256,768]
    const float* w_meta_inner = (const float*)d_in[4];  // [64,512]
    const float* w_out        = (const float*)d_in[5];  // [256,256]
    const float* b_out        = (const float*)d_in[6];  // [256]
    float* out = (float*)d_out;

    char* ws = (char*)d_ws;
    int* topidx = (int*)ws;                                    // 96 B
    unsigned int* cnt = (unsigned int*)(ws + 128);             // 64*4 = 256 B
    float* mm_part = (float*)(ws + 1024);                      // 16 KB
    unsigned short* WqkvT  = (unsigned short*)(ws + 20480);    // 768*256 bf16
    unsigned short* WmetaT = WqkvT + (size_t)768 * 256;        // 512*64
    unsigned short* Qc     = WmetaT + (size_t)512 * 64;        // 4096*512
    unsigned short* Kc     = Qc + (size_t)4096 * 512;          // 4096*512
    unsigned short* Vt     = Kc + (size_t)4096 * 512;          // 8*8*32*512
    unsigned short* AO     = Vt + (size_t)8 * 8 * 32 * 512;    // 4096*256

    prep<<<dim3(120), dim3(256), 0, stream>>>(
        w_qkv, w_meta_inner, metadata, WqkvT, WmetaT, mm_part);
    fused1<<<dim3(1281), dim3(256), 0, stream>>>(
        values, metadata, WqkvT, WmetaT, mm_part, w_meta_outer,
        Qc, Kc, Vt, topidx, cnt);
    attn_mfma<<<dim3(8, 8, 8), dim3(256), 0, stream>>>(
        topidx, Qc, Kc, Vt, AO, w_out, b_out, out, cnt);
}

// Round 10
// 124.059 us; speedup vs baseline: 1.7985x; 1.7985x over previous
//
#include <hip/hip_runtime.h>
#include <hip/hip_bf16.h>

// B=1, S=8, N=512, DV=256, DM=64, INNER=256, H=8, WS=3, DH=32
#define S_ 8
#define N_ 512
#define DV_ 256
#define DM_ 64
#define INNER_ 256
#define H_ 8
#define WS_ 3
#define DH_ 32

typedef __attribute__((ext_vector_type(8))) __bf16 bf16x8;
typedef __attribute__((ext_vector_type(4))) float f32x4;

__device__ __forceinline__ float clip5(float x) {
    return fminf(5.0f, fmaxf(-5.0f, x));
}
__device__ __forceinline__ unsigned short f2bf(float x) {
    __hip_bfloat16 h = __float2bfloat16(x);
    return *reinterpret_cast<unsigned short*>(&h);
}

// ---------------------------------------------------------------------------
// Kernel 0: prep — weight transposes (f32 -> bf16 W^T[n][k]) + meta_mean parts
// blocks 0..47:  w_qkv [256][768] -> WqkvT [768][256]
// blocks 48..55: w_meta_inner [64][512] -> WmetaT [512][64]
// blocks 56..71: w_out [256][256] -> WoutT [256][256]
// blocks 72..135: meta partial sums: block 72+s*8+g sums tokens [g*64,(g+1)*64)
//                 of source s -> mm_part[s][g][64]
// ---------------------------------------------------------------------------
__global__ __launch_bounds__(256) void prep(
    const float* __restrict__ w_qkv, const float* __restrict__ w_meta_inner,
    const float* __restrict__ w_out, const float* __restrict__ metadata,
    unsigned short* __restrict__ WqkvT, unsigned short* __restrict__ WmetaT,
    unsigned short* __restrict__ WoutT, float* __restrict__ mm_part)
{
    __shared__ float Tf[64][65];
    int b = blockIdx.x, tid = threadIdx.x;
    if (b < 72) {
        const float* src; unsigned short* dst; int Nsrc, Ktot, k0, n0;
        if (b < 48)      { src = w_qkv;        dst = WqkvT; Nsrc = 768; Ktot = 256; k0 = (b & 3) * 64; n0 = (b >> 2) * 64; }
        else if (b < 56) { src = w_meta_inner; dst = WmetaT; Nsrc = 512; Ktot = 64;  k0 = 0;            n0 = (b - 48) * 64; }
        else             { int t = b - 56; src = w_out; dst = WoutT; Nsrc = 256; Ktot = 256; k0 = (t & 3) * 64; n0 = (t >> 2) * 64; }
#pragma unroll
        for (int p = 0; p < 16; p++) {
            int i = p * 256 + tid; int r = i >> 6, cc = i & 63;
            Tf[r][cc] = src[(size_t)(k0 + r) * Nsrc + n0 + cc];
        }
        __syncthreads();
#pragma unroll
        for (int p = 0; p < 16; p++) {
            int i = p * 256 + tid; int r = i >> 6, cc = i & 63;
            dst[(size_t)(n0 + r) * Ktot + k0 + cc] = f2bf(Tf[cc][r]);
        }
    } else {
        int bb = b - 72;          // 0..63
        int s = bb >> 3, g = bb & 7;
        int d = tid & 63, t4 = tid >> 6;
        const float* base = metadata + ((size_t)(s * N_) + g * 64 + t4 * 16) * DM_ + d;
        float acc = 0.f;
#pragma unroll
        for (int i = 0; i < 16; i++) acc += base[(size_t)i * DM_];
        float* red = &Tf[0][0];
        red[tid] = acc;
        __syncthreads();
        if (tid < 64)
            mm_part[(size_t)bb * 64 + tid] =
                red[tid] + red[tid + 64] + red[tid + 128] + red[tid + 192];
    }
}

// ---------------------------------------------------------------------------
// Shared GEMM body (64x64 tile, 4 waves of 32x32), A f32 -> bf16 staged.
// ROLE 0: values @ WqkvT -> Qc/Kc (clip, qp|kp halves) + Vt
// ROLE 1: metadata @ WmetaT -> Qc/Kc (clip, qm|km halves)
// ---------------------------------------------------------------------------
template<int ROLE>
__device__ __forceinline__ void gemm_body(
    unsigned short* smem,
    const float* __restrict__ A, const unsigned short* __restrict__ Bt,
    unsigned short* __restrict__ Qc, unsigned short* __restrict__ Kc,
    unsigned short* __restrict__ Vt,
    int m0, int n0g, int tid)
{
    constexpr int K = (ROLE == 1) ? 64 : 256;
    constexpr int KP = K + 8;  // 16B-aligned rows, 2-way LDS aliasing only (free)
    unsigned short* As = smem;
    unsigned short* Bs = smem + 64 * KP;

    for (int i = tid; i < 64 * (K / 4); i += 256) {
        int r = i / (K / 4), g = i % (K / 4);
        float4 x = *(const float4*)(A + (size_t)(m0 + r) * K + 4 * g);
        *(ushort4*)&As[r * KP + 4 * g] =
            make_ushort4(f2bf(x.x), f2bf(x.y), f2bf(x.z), f2bf(x.w));
    }
    for (int i = tid; i < 64 * (K / 8); i += 256) {
        int r = i / (K / 8), g = i % (K / 8);
        *(bf16x8*)&Bs[r * KP + 8 * g] =
            *(const bf16x8*)(Bt + (size_t)(n0g + r) * K + 8 * g);
    }
    __syncthreads();

    const int w = tid >> 6, lane = tid & 63, c = lane & 15, qd = lane >> 4;
    const int mb = (w >> 1) * 32, nb = (w & 1) * 32;
    f32x4 acc[2][2];
    const f32x4 z = {0.f, 0.f, 0.f, 0.f};
#pragma unroll
    for (int mt = 0; mt < 2; mt++)
#pragma unroll
        for (int nt = 0; nt < 2; nt++) acc[mt][nt] = z;

#pragma unroll
    for (int kk = 0; kk < K / 32; kk++) {
        bf16x8 a[2], bb[2];
#pragma unroll
        for (int mt = 0; mt < 2; mt++)
            a[mt] = *(const bf16x8*)&As[(mb + mt * 16 + c) * KP + kk * 32 + qd * 8];
#pragma unroll
        for (int nt = 0; nt < 2; nt++)
            bb[nt] = *(const bf16x8*)&Bs[(nb + nt * 16 + c) * KP + kk * 32 + qd * 8];
#pragma unroll
        for (int mt = 0; mt < 2; mt++)
#pragma unroll
            for (int nt = 0; nt < 2; nt++)
                acc[mt][nt] = __builtin_amdgcn_mfma_f32_16x16x32_bf16(
                    a[mt], bb[nt], acc[mt][nt], 0, 0, 0);
    }

#pragma unroll
    for (int mt = 0; mt < 2; mt++)
#pragma unroll
        for (int nt = 0; nt < 2; nt++)
#pragma unroll
            for (int r = 0; r < 4; r++) {
                int tok = m0 + mb + mt * 16 + qd * 4 + r;
                int n = n0g + nb + nt * 16 + c;
                float v = acc[mt][nt][r];
                if (ROLE == 0) {
                    if (n < 512) {
                        unsigned short* dst = (n < 256) ? Qc : Kc;
                        int p = n & 255;
                        dst[(size_t)tok * 512 + (p >> 5) * 64 + (p & 31)] = f2bf(clip5(v));
                    } else {
                        int vc = n - 512, h = vc >> 5, dh = vc & 31;
                        int s = tok >> 9, ntok = tok & 511;
                        Vt[(size_t)((s * 8 + h) * 32 + dh) * 512 + ntok] = f2bf(v);
                    }
                } else {
                    unsigned short* dst = (n < 256) ? Qc : Kc;
                    int p = n & 255;
                    dst[(size_t)tok * 512 + (p >> 5) * 64 + 32 + (p & 31)] = f2bf(clip5(v));
                }
            }
}

// ---------------------------------------------------------------------------
// Kernel 1: fused — block 0: mm reduce + outer topk; blocks 1..768: values
// GEMM; blocks 769..1280: metadata GEMM. All independent.
// ---------------------------------------------------------------------------
__global__ __launch_bounds__(256) void fused1(
    const float* __restrict__ values, const float* __restrict__ metadata,
    const unsigned short* __restrict__ WqkvT,
    const unsigned short* __restrict__ WmetaT,
    const float* __restrict__ mm_part, const float* __restrict__ w_meta_outer,
    unsigned short* __restrict__ Qc, unsigned short* __restrict__ Kc,
    unsigned short* __restrict__ Vt, int* __restrict__ topidx)
{
    __shared__ __align__(16) unsigned short smem[2 * 64 * 264];  // 66 KB
    const int b = blockIdx.x, tid = threadIdx.x;

    if (b == 0) {
        // ---- reduce meta_mean partials, then outer attention + top-3 ----
        float* mml  = (float*)smem;            // [8][64]
        float* qmS  = mml + 512;               // [8][256]
        float* kmS  = qmS + 2048;              // [8][256]
        float* dots = kmS + 2048;              // [8][8]
        for (int i = tid; i < 512; i += 256) {
            int s = i >> 6, d = i & 63;
            float acc = 0.f;
#pragma unroll
            for (int g = 0; g < 8; g++) acc += mm_part[(size_t)(s * 8 + g) * 64 + d];
            mml[i] = acc * (1.0f / (float)N_);
        }
        __syncthreads();
        for (int i = tid; i < S_ * 512; i += 256) {
            int s = i >> 9, c = i & 511;
            float acc = 0.0f;
            for (int k = 0; k < DM_; k++) acc += mml[s * 64 + k] * w_meta_outer[k * 512 + c];
            acc = clip5(acc);
            if (c < 256) qmS[s * 256 + c] = acc; else kmS[s * 256 + c - 256] = acc;
        }
        __syncthreads();
        if (tid < 64) {
            int qi = tid >> 3, ki = tid & 7;
            float acc = 0.0f;
            for (int j = 0; j < INNER_; j++) acc += qmS[qi * 256 + j] * kmS[ki * 256 + j];
            dots[qi * 8 + ki] = acc * 0.0625f;  // 1/sqrt(256)
        }
        __syncthreads();
        if (tid < S_) {
            int r = tid;
            float mx = -1e30f;
            for (int k = 0; k < S_; k++) mx = fmaxf(mx, dots[r * 8 + k]);
            float e[S_], sum = 0.0f;
            for (int k = 0; k < S_; k++) { e[k] = __expf(dots[r * 8 + k] - mx); sum += e[k]; }
            float vals[S_];
            for (int k = 0; k < S_; k++) vals[k] = e[k] / sum + (k == r ? 2.0f : 0.0f);
            bool used[S_];
            for (int k = 0; k < S_; k++) used[k] = false;
            for (int w = 0; w < WS_; w++) {
                float best = -1e30f; int bi = 0;
                for (int k = 0; k < S_; k++) {
                    if (!used[k] && vals[k] > best) { best = vals[k]; bi = k; }
                }
                used[bi] = true;
                topidx[r * WS_ + w] = bi;
            }
        }
    } else if (b <= 768) {
        int g = b - 1;
        gemm_body<0>(smem, values, WqkvT, Qc, Kc, Vt, (g & 63) * 64, (g >> 6) * 64, tid);
    } else {
        int g = b - 769;
        gemm_body<1>(smem, metadata, WmetaT, Qc, Kc, Vt, (g & 63) * 64, (g >> 6) * 64, tid);
    }
}

// ---------------------------------------------------------------------------
// Kernel 2: MFMA flash attention (AO bf16)
// ---------------------------------------------------------------------------
__global__ __launch_bounds__(256) void attn_mfma(
    const int* __restrict__ topidx,
    const unsigned short* __restrict__ Qc,   // [4096][8][64] bf16
    const unsigned short* __restrict__ Kc,   // [4096][8][64] bf16
    const unsigned short* __restrict__ Vt,   // [8][8][32][512] bf16
    unsigned short* __restrict__ AO)         // [4096][256] bf16
{
    const int s   = blockIdx.x;
    const int h   = blockIdx.y;
    const int qt  = blockIdx.z;
    const int tid = threadIdx.x;
    const int w    = tid >> 6;
    const int lane = tid & 63;
    const int c    = lane & 15;
    const int qd   = lane >> 4;
    const float scale = 0.17677669529663687f;  // 1/sqrt(32)

    __shared__ __align__(16) unsigned short Pq[4][64][40];  // [wave][q][key+pad]
    __shared__ __align__(16) float Of[4][32][66];           // [wave][dh][q+pad]
    __shared__ float Ml[4][2][64];                          // [wave][m/l][q]

    const int src0 = topidx[s * WS_ + 0];
    const int srcs[3] = { topidx[s * WS_ + 0], topidx[s * WS_ + 1], topidx[s * WS_ + 2] };

    bf16x8 qf[4][2];
    {
        const unsigned short* qbase =
            Qc + (size_t)(src0 * N_ + qt * 64) * 512 + h * 64 + qd * 8;
#pragma unroll
        for (int qg = 0; qg < 4; qg++)
#pragma unroll
            for (int kc = 0; kc < 2; kc++)
                qf[qg][kc] = *reinterpret_cast<const bf16x8*>(
                    qbase + (size_t)(qg * 16 + c) * 512 + kc * 32);
    }

    f32x4 oacc[2][4];
    const f32x4 zero4 = {0.f, 0.f, 0.f, 0.f};
#pragma unroll
    for (int mg = 0; mg < 2; mg++)
#pragma unroll
        for (int qg = 0; qg < 4; qg++) oacc[mg][qg] = zero4;
    float mrun[4], lrun[4];
#pragma unroll
    for (int qg = 0; qg < 4; qg++) { mrun[qg] = -3.0e38f; lrun[qg] = 0.f; }

    for (int step = 0; step < 12; step++) {
        const int chunk = step * 4 + w;
        const int src = srcs[chunk >> 4];
        const int klocal = (chunk & 15) * 32;

        bf16x8 kf[2][2];
        const unsigned short* kbase =
            Kc + (size_t)(src * N_ + klocal) * 512 + h * 64 + qd * 8;
#pragma unroll
        for (int mg = 0; mg < 2; mg++)
#pragma unroll
            for (int kc = 0; kc < 2; kc++)
                kf[mg][kc] = *reinterpret_cast<const bf16x8*>(
                    kbase + (size_t)(mg * 16 + c) * 512 + kc * 32);

        bf16x8 vf[2];
        const unsigned short* vbase =
            Vt + (size_t)((src * H_ + h) * DH_) * N_ + klocal + qd * 8;
#pragma unroll
        for (int mg = 0; mg < 2; mg++)
            vf[mg] = *reinterpret_cast<const bf16x8*>(vbase + (size_t)(mg * 16 + c) * N_);

        f32x4 sacc[2][4];
#pragma unroll
        for (int mg = 0; mg < 2; mg++)
#pragma unroll
            for (int qg = 0; qg < 4; qg++) sacc[mg][qg] = zero4;
#pragma unroll
        for (int kc = 0; kc < 2; kc++)
#pragma unroll
            for (int mg = 0; mg < 2; mg++)
#pragma unroll
                for (int qg = 0; qg < 4; qg++)
                    sacc[mg][qg] = __builtin_amdgcn_mfma_f32_16x16x32_bf16(
                        kf[mg][kc], qf[qg][kc], sacc[mg][qg], 0, 0, 0);

#pragma unroll
        for (int qg = 0; qg < 4; qg++) {
            float mx = sacc[0][qg][0];
#pragma unroll
            for (int r = 1; r < 4; r++) mx = fmaxf(mx, sacc[0][qg][r]);
#pragma unroll
            for (int r = 0; r < 4; r++) mx = fmaxf(mx, sacc[1][qg][r]);
            mx = fmaxf(mx, __shfl_xor(mx, 16));
            mx = fmaxf(mx, __shfl_xor(mx, 32));
            float mnew = fmaxf(mrun[qg], mx);
            float alpha = __expf((mrun[qg] - mnew) * scale);
            float msc = mnew * scale;
            float ps = 0.f;
            unsigned short pb[2][4];
#pragma unroll
            for (int mg = 0; mg < 2; mg++)
#pragma unroll
                for (int r = 0; r < 4; r++) {
                    float p = __expf(__builtin_fmaf(sacc[mg][qg][r], scale, -msc));
                    ps += p;
                    pb[mg][r] = f2bf(p);
                }
            ps += __shfl_xor(ps, 16);
            ps += __shfl_xor(ps, 32);
            lrun[qg] = lrun[qg] * alpha + ps;
            mrun[qg] = mnew;
#pragma unroll
            for (int mg = 0; mg < 2; mg++)
#pragma unroll
                for (int r = 0; r < 4; r++) oacc[mg][qg][r] *= alpha;
#pragma unroll
            for (int mg = 0; mg < 2; mg++) {
                ushort4 u = make_ushort4(pb[mg][0], pb[mg][1], pb[mg][2], pb[mg][3]);
                *reinterpret_cast<ushort4*>(&Pq[w][qg * 16 + c][mg * 16 + qd * 4]) = u;
            }
        }

        bf16x8 pf[4];
#pragma unroll
        for (int qg = 0; qg < 4; qg++)
            pf[qg] = *reinterpret_cast<const bf16x8*>(&Pq[w][qg * 16 + c][qd * 8]);
#pragma unroll
        for (int mg = 0; mg < 2; mg++)
#pragma unroll
            for (int qg = 0; qg < 4; qg++)
                oacc[mg][qg] = __builtin_amdgcn_mfma_f32_16x16x32_bf16(
                    vf[mg], pf[qg], oacc[mg][qg], 0, 0, 0);
    }

    __syncthreads();
#pragma unroll
    for (int qg = 0; qg < 4; qg++) {
        if (qd == 0) {
            Ml[w][0][qg * 16 + c] = mrun[qg];
            Ml[w][1][qg * 16 + c] = lrun[qg];
        }
#pragma unroll
        for (int mg = 0; mg < 2; mg++)
#pragma unroll
            for (int r = 0; r < 4; r++)
                Of[w][mg * 16 + qd * 4 + r][qg * 16 + c] = oacc[mg][qg][r];
    }
    __syncthreads();

    {
        int q = tid & 63;
        int dh0 = (tid >> 6) * 8;
        float mw[4], cw[4];
#pragma unroll
        for (int v = 0; v < 4; v++) mw[v] = Ml[v][0][q];
        float M = fmaxf(fmaxf(mw[0], mw[1]), fmaxf(mw[2], mw[3]));
        float L = 0.f;
#pragma unroll
        for (int v = 0; v < 4; v++) {
            cw[v] = __expf((mw[v] - M) * scale);
            L += cw[v] * Ml[v][1][q];
        }
        float inv = 1.0f / L;
        unsigned short* aorow =
            AO + (size_t)(s * N_ + qt * 64 + q) * 256 + h * 32 + dh0;
        unsigned short ub[8];
#pragma unroll
        for (int j = 0; j < 8; j++) {
            int dh = dh0 + j;
            float o = cw[0] * Of[0][dh][q] + cw[1] * Of[1][dh][q]
                    + cw[2] * Of[2][dh][q] + cw[3] * Of[3][dh][q];
            ub[j] = f2bf(o * inv);
        }
        uint4 u;
        u.x = (unsigned)ub[0] | ((unsigned)ub[1] << 16);
        u.y = (unsigned)ub[2] | ((unsigned)ub[3] << 16);
        u.z = (unsigned)ub[4] | ((unsigned)ub[5] << 16);
        u.w = (unsigned)ub[6] | ((unsigned)ub[7] << 16);
        *reinterpret_cast<uint4*>(aorow) = u;
    }
}

// ---------------------------------------------------------------------------
// Kernel 3: output projection AO(bf16) @ WoutT + b_out -> out f32
// ---------------------------------------------------------------------------
__global__ __launch_bounds__(256) void gemm_out(
    const unsigned short* __restrict__ AO, const unsigned short* __restrict__ Bt,
    const float* __restrict__ bias, float* __restrict__ outp)
{
    constexpr int K = 256;
    constexpr int KP = K + 8;
    __shared__ __align__(16) unsigned short As[64 * KP];
    __shared__ __align__(16) unsigned short Bs[64 * KP];
    const int tid = threadIdx.x;
    const int m0 = blockIdx.x * 64;
    const int n0g = blockIdx.y * 64;

    for (int i = tid; i < 64 * (K / 8); i += 256) {
        int r = i / (K / 8), g = i % (K / 8);
        *(bf16x8*)&As[r * KP + 8 * g] =
            *(const bf16x8*)(AO + (size_t)(m0 + r) * K + 8 * g);
    }
    for (int i = tid; i < 64 * (K / 8); i += 256) {
        int r = i / (K / 8), g = i % (K / 8);
        *(bf16x8*)&Bs[r * KP + 8 * g] =
            *(const bf16x8*)(Bt + (size_t)(n0g + r) * K + 8 * g);
    }
    __syncthreads();

    const int w = tid >> 6, lane = tid & 63, c = lane & 15, qd = lane >> 4;
    const int mb = (w >> 1) * 32, nb = (w & 1) * 32;
    f32x4 acc[2][2];
    const f32x4 z = {0.f, 0.f, 0.f, 0.f};
#pragma unroll
    for (int mt = 0; mt < 2; mt++)
#pragma unroll
        for (int nt = 0; nt < 2; nt++) acc[mt][nt] = z;

#pragma unroll
    for (int kk = 0; kk < K / 32; kk++) {
        bf16x8 a[2], bb[2];
#pragma unroll
        for (int mt = 0; mt < 2; mt++)
            a[mt] = *(const bf16x8*)&As[(mb + mt * 16 + c) * KP + kk * 32 + qd * 8];
#pragma unroll
        for (int nt = 0; nt < 2; nt++)
            bb[nt] = *(const bf16x8*)&Bs[(nb + nt * 16 + c) * KP + kk * 32 + qd * 8];
#pragma unroll
        for (int mt = 0; mt < 2; mt++)
#pragma unroll
            for (int nt = 0; nt < 2; nt++)
                acc[mt][nt] = __builtin_amdgcn_mfma_f32_16x16x32_bf16(
                    a[mt], bb[nt], acc[mt][nt], 0, 0, 0);
    }

#pragma unroll
    for (int mt = 0; mt < 2; mt++)
#pragma unroll
        for (int nt = 0; nt < 2; nt++)
#pragma unroll
            for (int r = 0; r < 4; r++) {
                int tok = m0 + mb + mt * 16 + qd * 4 + r;
                int n = n0g + nb + nt * 16 + c;
                outp[(size_t)tok * 256 + n] = acc[mt][nt][r] + bias[n];
            }
}

// ---------------------------------------------------------------------------
extern "C" void kernel_launch(void* const* d_in, const int* in_sizes, int n_in,
                              void* d_out, int out_size, void* d_ws, size_t ws_size,
                              hipStream_t stream) {
    const float* values       = (const float*)d_in[0];  // [1,8,512,256]
    const float* metadata     = (const float*)d_in[1];  // [1,8,512,64]
    const float* w_meta_outer = (const float*)d_in[2];  // [64,512]
    const float* w_qkv        = (const float*)d_in[3];  // [256,768]
    const float* w_meta_inner = (const float*)d_in[4];  // [64,512]
    const float* w_out        = (const float*)d_in[5];  // [256,256]
    const float* b_out        = (const float*)d_in[6];  // [256]
    float* out = (float*)d_out;

    char* ws = (char*)d_ws;
    int* topidx = (int*)ws;                                    // 128 B
    float* mm_part = (float*)(ws + 256);                       // 64*64 f32 = 16 KB
    unsigned short* WqkvT  = (unsigned short*)(ws + 20480);    // 768*256 bf16
    unsigned short* WmetaT = WqkvT + (size_t)768 * 256;        // 512*64
    unsigned short* WoutT  = WmetaT + (size_t)512 * 64;        // 256*256
    unsigned short* Qc     = WoutT + (size_t)256 * 256;        // 4096*512
    unsigned short* Kc     = Qc + (size_t)4096 * 512;          // 4096*512
    unsigned short* Vt     = Kc + (size_t)4096 * 512;          // 8*8*32*512
    unsigned short* AO     = Vt + (size_t)8 * 8 * 32 * 512;    // 4096*256

    prep<<<dim3(136), dim3(256), 0, stream>>>(
        w_qkv, w_meta_inner, w_out, metadata, WqkvT, WmetaT, WoutT, mm_part);
    fused1<<<dim3(1281), dim3(256), 0, stream>>>(
        values, metadata, WqkvT, WmetaT, mm_part, w_meta_outer, Qc, Kc, Vt, topidx);
    attn_mfma<<<dim3(8, 8, 8), dim3(256), 0, stream>>>(topidx, Qc, Kc, Vt, AO);
    gemm_out<<<dim3(64, 4), dim3(256), 0, stream>>>(AO, WoutT, b_out, out);
}